// Round 6
// baseline (126.647 us; speedup 1.0000x reference)
//
#include <hip/hip_runtime.h>
#include <math.h>

// VectorQuantizer on MI355X — R16 == R15 resubmit (R15 bench died to an infra
// container failure before running; source re-audited, unchanged).
// R15: occupancy attack on vq_main.
// R13 counters: MfmaUtil 3.8 / VALUBusy 11 / Occ 26% / traffic 56 MB (~9 µs
// roofline) -> latency-bound at 2 blocks/CU. Sole cap = 64 KB LDS codebook.
// Split-K: stage 256 codes (32 KB) -> scan -> restage other 256 -> scan.
// runkey min carries across passes (key has full 9-bit code); argmin
// semantics identical. LDS 69.5->37.4 KB => 4 blocks/CU; grid 512->1024 with
// 128 tokens/block fills the slots; __launch_bounds__(512,8) caps VGPR at 64
// for 32 waves/CU. W restaged 2x (L2-hot, invisible in FETCH). pcounts u8
// (hist<=128) keeps the final pull at 512 KB despite 2x rows.
// Lessons kept: no nontemporal out (R12: +43MB HBM writes), no cross-block
// fences (R13: ~40 µs), plain cached epilogue stores.
// ws: [0,512K) pcounts u8[1024][512] | [512K,+8K) ssep f64[1024]

#define NTOK 131072
#define KCODES 512
#define HW 4096
#define CHW 262144
#define NELEM 8388608

typedef __attribute__((ext_vector_type(8))) short short8;
typedef __attribute__((ext_vector_type(4))) float f32x4;

static __device__ __forceinline__ unsigned short f2bf(float f) {
    unsigned u = __float_as_uint(f);
    unsigned r = u + 0x7FFFu + ((u >> 16) & 1u);  // RNE
    return (unsigned short)(r >> 16);
}

__global__ __launch_bounds__(512, 8) void vq_main(const float* __restrict__ in,
                                                  const float* __restrict__ w,
                                                  float* __restrict__ out,
                                                  unsigned char* __restrict__ pcounts,
                                                  double* __restrict__ ssep,
                                                  float* __restrict__ counts,
                                                  double* __restrict__ sse_acc,
                                                  const int amode) {
    __shared__ __align__(16) unsigned short wh[256 * 64];  // 32768 B bf16 half-codebook
    __shared__ float wsqp[KCODES];              // 2048 B: 1.25 + ||w_k||^2
    __shared__ int idxbuf[128];                 // 512 B
    __shared__ int hist[KCODES];                // 2048 B block histogram
    __shared__ double sred[8];                  // per-wave sse partials

    const int tid = threadIdx.x;
    const int lane = tid & 63, wv = tid >> 6;   // wv in [0,8)
    const int col = lane & 15, quad = lane >> 4;
    const int ntok0 = blockIdx.x * 128;         // 1024 blocks x 128 tokens

    wsqp[tid] = 1.25f;
    hist[tid] = 0;
    __syncthreads();  // B1: wsqp/hist init before use

    // ---- pass-0 staging (codes 0..255) interleaved with ALL X loads ----
    // Per thread: 4 W-chunks (float4-pair each) + 16 X dwords (token wv*16+col,
    // channels quad*8+j / 32+quad*8+j). ah packed in place (keeps VGPR low;
    // TLP from 32 waves/CU replaces ILP hoisting).
    const float* gbase = in + (ntok0 >> 12) * CHW + (ntok0 & 4095) + wv * 16 + col;
    short8 ah[2];
    float xsq = 0.f;
#pragma unroll
    for (int it = 0; it < 4; ++it) {
        const int g = it * 512 + tid;  // [0,2048): 256 codes x 8 chunks
        const int cc = g & 15, qd = (g >> 4) & 3, ch = (g >> 6) & 1, tt = g >> 7;
        const int code = tt * 16 + cc;
        const float4* src = (const float4*)(w + code * 64 + ch * 32 + qd * 8);
        const float4 v0 = src[0], v1 = src[1];
        const int c = it >> 1, j0 = (it & 1) * 4;
        const float* gp = gbase + (c * 32 + quad * 8 + j0) * HW;
        const float x0 = gp[0 * HW], x1 = gp[1 * HW], x2 = gp[2 * HW], x3 = gp[3 * HW];

        short8 hv;
        hv[0] = (short)f2bf(v0.x); hv[1] = (short)f2bf(v0.y);
        hv[2] = (short)f2bf(v0.z); hv[3] = (short)f2bf(v0.w);
        hv[4] = (short)f2bf(v1.x); hv[5] = (short)f2bf(v1.y);
        hv[6] = (short)f2bf(v1.z); hv[7] = (short)f2bf(v1.w);
        *(short8*)(wh + g * 8) = hv;
        float ws2 = v0.x * v0.x;
        ws2 = fmaf(v0.y, v0.y, ws2); ws2 = fmaf(v0.z, v0.z, ws2);
        ws2 = fmaf(v0.w, v0.w, ws2); ws2 = fmaf(v1.x, v1.x, ws2);
        ws2 = fmaf(v1.y, v1.y, ws2); ws2 = fmaf(v1.z, v1.z, ws2);
        ws2 = fmaf(v1.w, v1.w, ws2);
        atomicAdd(&wsqp[code], ws2);  // LDS atomic

        ah[c][j0 + 0] = (short)f2bf(-2.0f * x0);
        ah[c][j0 + 1] = (short)f2bf(-2.0f * x1);
        ah[c][j0 + 2] = (short)f2bf(-2.0f * x2);
        ah[c][j0 + 3] = (short)f2bf(-2.0f * x3);
        xsq = fmaf(x0, x0, xsq); xsq = fmaf(x1, x1, xsq);
        xsq = fmaf(x2, x2, xsq); xsq = fmaf(x3, x3, xsq);
    }
    __syncthreads();  // B2: pass-0 wh + wsqp[0:256] complete

    unsigned runkey[4];
#pragma unroll
    for (int r = 0; r < 4; ++r) runkey[r] = 0xFFFFFFFFu;

    // ---- scan pass 0: tiles 0..15 (codes 0..255) ----
#pragma unroll 1
    for (int t = 0; t < 16; ++t) {
        const unsigned short* ph = wh + t * 1024 + quad * 128 + col * 8;
        const short8 b0 = *(const short8*)ph;
        const short8 b1 = *(const short8*)(ph + 512);
        const int code = t * 16 + col;
        const float seed = wsqp[code];
        f32x4 acc = {seed, seed, seed, seed};
        acc = __builtin_amdgcn_mfma_f32_16x16x32_bf16(ah[0], b0, acc, 0, 0, 0);
        acc = __builtin_amdgcn_mfma_f32_16x16x32_bf16(ah[1], b1, acc, 0, 0, 0);
#pragma unroll
        for (int r = 0; r < 4; ++r) {
            const unsigned key = (__float_as_uint(acc[r]) << 9) | code;
            runkey[r] = key < runkey[r] ? key : runkey[r];
        }
    }
    __syncthreads();  // B3: all waves done reading pass-0 wh

    // ---- pass-1 staging (codes 256..511) ----
#pragma unroll
    for (int it = 0; it < 4; ++it) {
        const int g = it * 512 + tid;
        const int cc = g & 15, qd = (g >> 4) & 3, ch = (g >> 6) & 1, tt = g >> 7;
        const int code = 256 + tt * 16 + cc;
        const float4* src = (const float4*)(w + code * 64 + ch * 32 + qd * 8);
        const float4 v0 = src[0], v1 = src[1];
        short8 hv;
        hv[0] = (short)f2bf(v0.x); hv[1] = (short)f2bf(v0.y);
        hv[2] = (short)f2bf(v0.z); hv[3] = (short)f2bf(v0.w);
        hv[4] = (short)f2bf(v1.x); hv[5] = (short)f2bf(v1.y);
        hv[6] = (short)f2bf(v1.z); hv[7] = (short)f2bf(v1.w);
        *(short8*)(wh + g * 8) = hv;
        float ws2 = v0.x * v0.x;
        ws2 = fmaf(v0.y, v0.y, ws2); ws2 = fmaf(v0.z, v0.z, ws2);
        ws2 = fmaf(v0.w, v0.w, ws2); ws2 = fmaf(v1.x, v1.x, ws2);
        ws2 = fmaf(v1.y, v1.y, ws2); ws2 = fmaf(v1.z, v1.z, ws2);
        ws2 = fmaf(v1.w, v1.w, ws2);
        atomicAdd(&wsqp[code], ws2);
    }
    __syncthreads();  // B4: pass-1 wh + wsqp[256:512] complete

    // ---- scan pass 1: codes 256..511 ----
#pragma unroll 1
    for (int t = 0; t < 16; ++t) {
        const unsigned short* ph = wh + t * 1024 + quad * 128 + col * 8;
        const short8 b0 = *(const short8*)ph;
        const short8 b1 = *(const short8*)(ph + 512);
        const int code = 256 + t * 16 + col;
        const float seed = wsqp[code];
        f32x4 acc = {seed, seed, seed, seed};
        acc = __builtin_amdgcn_mfma_f32_16x16x32_bf16(ah[0], b0, acc, 0, 0, 0);
        acc = __builtin_amdgcn_mfma_f32_16x16x32_bf16(ah[1], b1, acc, 0, 0, 0);
#pragma unroll
        for (int r = 0; r < 4; ++r) {
            const unsigned key = (__float_as_uint(acc[r]) << 9) | code;
            runkey[r] = key < runkey[r] ? key : runkey[r];
        }
    }

    // ---- cross-lane argmin over the 16 code-cols ----
#pragma unroll
    for (int s = 1; s < 16; s <<= 1)
#pragma unroll
        for (int r = 0; r < 4; ++r) {
            const unsigned o = __shfl_xor(runkey[r], s, 64);
            runkey[r] = o < runkey[r] ? o : runkey[r];
        }

    // d_best (exact from key; acc in [1,2) by 1.25 seed) + publish indices
    float dsum = 0.f;
    if (col == 0) {
#pragma unroll
        for (int r = 0; r < 4; ++r) {
            const unsigned key = runkey[r];
            idxbuf[wv * 16 + quad * 4 + r] = (int)(key & 511u);
            dsum += __uint_as_float((key >> 9) | 0x3F800000u) - 1.25f;
        }
    }
    float contrib = xsq + dsum;
#pragma unroll
    for (int off = 32; off > 0; off >>= 1) contrib += __shfl_down(contrib, off, 64);
    if (lane == 0) sred[wv] = (double)contrib;

    // per-wave histogram over wave-local idxbuf (no extra barrier needed)
    if (lane < 16) atomicAdd(&hist[idxbuf[wv * 16 + lane]], 1);

    // ---- epilogue: 16 tokens/wave, 4 lanes/token; plain cached stores ----
    {
        const int tl = lane >> 2, q = lane & 3;
        const int n = ntok0 + wv * 16 + tl;
        const int bidx = idxbuf[wv * 16 + tl];
        const float4* wr = (const float4*)(w + bidx * 64 + q * 16);
        float4* op = (float4*)(out + n * 64 + q * 16);
#pragma unroll
        for (int i = 0; i < 4; ++i) op[i] = wr[i];
    }
    __syncthreads();  // B5: hist + sred complete

    if (!amode) {
        pcounts[(blockIdx.x << 9) + tid] = (unsigned char)hist[tid];  // <=128
        if (tid == 0) {
            double s = sred[0];
#pragma unroll
            for (int i = 1; i < 8; ++i) s += sred[i];
            ssep[blockIdx.x] = s;
        }
    } else {  // fallback: ws too small for partials
        const int h = hist[tid];
        if (h) atomicAdd(&counts[tid], (float)h);
        if (tid == 0) {
            double s = sred[0];
#pragma unroll
            for (int i = 1; i < 8; ++i) s += sred[i];
            atomicAdd(sse_acc, s);
        }
    }
}

// parallel reduce: thread t owns 4 codes x 1 row-quarter (256 rows); uint
// loads, per-byte extract, integer accumulate (exact).
__global__ __launch_bounds__(512) void vq_final_p(const unsigned char* __restrict__ pcounts,
                                                  const double* __restrict__ ssep,
                                                  float* __restrict__ out) {
    __shared__ unsigned part[4][512];  // 8 KB: quarter x code
    __shared__ double red[512];
    __shared__ double sred[512];
    const int t = threadIdx.x;
    const int q = t >> 7, c4 = (t & 127) << 2;

    const unsigned* base = (const unsigned*)(pcounts + (size_t)(q << 8) * 512 + c4);
    unsigned s0 = 0, s1 = 0, s2 = 0, s3 = 0;
#pragma unroll 16
    for (int b = 0; b < 256; ++b) {        // rows q*256 .. q*256+255
        const unsigned v = base[b << 7];   // stride 512 B = 128 uints
        s0 += v & 255u; s1 += (v >> 8) & 255u;
        s2 += (v >> 16) & 255u; s3 += v >> 24;
    }
    part[q][c4] = s0; part[q][c4 + 1] = s1;
    part[q][c4 + 2] = s2; part[q][c4 + 3] = s3;
    sred[t] = ssep[t] + ssep[t + 512];
    __syncthreads();

    const float cnt = (float)(part[0][t] + part[1][t] + part[2][t] + part[3][t]);
    const double p = (double)cnt / (double)NTOK;
    red[t] = p * log(p + 1e-10);
    __syncthreads();
#pragma unroll
    for (int st = 256; st > 0; st >>= 1) {
        if (t < st) { red[t] += red[t + st]; sred[t] += sred[t + st]; }
        __syncthreads();
    }
    if (t == 0) {
        out[NELEM] = (float)((sred[0] / (double)NELEM) * 1.25);
        out[NELEM + 1] = (float)exp(-red[0]);
    }
}

__global__ __launch_bounds__(512) void vq_final_a(const float* __restrict__ counts,
                                                  const double* __restrict__ sse_acc,
                                                  float* __restrict__ out) {
    __shared__ double red[512];
    const int k = threadIdx.x;
    const double p = (double)counts[k] / (double)NTOK;
    red[k] = p * log(p + 1e-10);
    __syncthreads();
#pragma unroll
    for (int st = 256; st > 0; st >>= 1) {
        if (k < st) red[k] += red[k + st];
        __syncthreads();
    }
    if (k == 0) {
        out[NELEM] = (float)((*sse_acc / (double)NELEM) * 1.25);
        out[NELEM + 1] = (float)exp(-red[0]);
    }
}

extern "C" void kernel_launch(void* const* d_in, const int* in_sizes, int n_in,
                              void* d_out, int out_size, void* d_ws, size_t ws_size,
                              hipStream_t stream) {
    const float* in = (const float*)d_in[0];
    const float* w = (const float*)d_in[1];
    float* out = (float*)d_out;
    char* ws = (char*)d_ws;

    const size_t SS = (size_t)1024 * 512;         // 512 KB of u8 partials
    const size_t need = SS + 1024 * 8;            // + ssep f64[1024]
    if (ws_size >= need) {
        unsigned char* pcounts = (unsigned char*)ws;
        double* ssep = (double*)(ws + SS);
        vq_main<<<1024, 512, 0, stream>>>(in, w, out, pcounts, ssep,
                                          nullptr, nullptr, 0);
        vq_final_p<<<1, 512, 0, stream>>>(pcounts, ssep, out);
    } else {  // fallback: R6-style atomics
        float* counts = (float*)ws;
        double* sse_acc = (double*)(ws + 2048);
        (void)hipMemsetAsync(ws, 0, 2056, stream);
        vq_main<<<1024, 512, 0, stream>>>(in, w, out, nullptr, nullptr,
                                          counts, sse_acc, 1);
        vq_final_a<<<1, 512, 0, stream>>>(counts, sse_acc, out);
    }
}

// Round 7
// 116.497 us; speedup vs baseline: 1.0871x; 1.0871x over previous
//
#include <hip/hip_runtime.h>
#include <math.h>

// VectorQuantizer on MI355X — R17: split-K occupancy WITHOUT staging blowup.
// R16 post-mortem: 4 blocks/CU achieved (Occ 26->60%) but halving tokens/block
// doubled total W-staging (VALUBusy 11->27%) and net-regressed. R17 keeps the
// 32 KB half-codebook LDS (the occupancy unlock) at 512 blocks x 256 tokens:
// staging work = R14's 1x, occupancy = R16's 4 blocks/CU. In-place packing
// (R16, VGPR 28) fits the 64-VGPR cap of __launch_bounds__(512,8).
// pcounts u16 (hist<=256; u8 overflows). Clean A/B vs R14: same work, 2x occ.
// Lessons kept: no nontemporal out (R12 +43MB), no cross-block fences (R13
// ~40µs), plain cached epilogue, two-kernel structure.
// ws: [0,512K) pcounts u16[512][512] | [512K,+4K) ssep f64[512]

#define NTOK 131072
#define KCODES 512
#define HW 4096
#define CHW 262144
#define NELEM 8388608

typedef __attribute__((ext_vector_type(8))) short short8;
typedef __attribute__((ext_vector_type(4))) float f32x4;
typedef __attribute__((ext_vector_type(4))) unsigned short u16x4;

static __device__ __forceinline__ unsigned short f2bf(float f) {
    unsigned u = __float_as_uint(f);
    unsigned r = u + 0x7FFFu + ((u >> 16) & 1u);  // RNE
    return (unsigned short)(r >> 16);
}

__global__ __launch_bounds__(512, 8) void vq_main(const float* __restrict__ in,
                                                  const float* __restrict__ w,
                                                  float* __restrict__ out,
                                                  unsigned short* __restrict__ pcounts,
                                                  double* __restrict__ ssep,
                                                  float* __restrict__ counts,
                                                  double* __restrict__ sse_acc,
                                                  const int amode) {
    __shared__ __align__(16) unsigned short wh[256 * 64];  // 32768 B half-codebook
    __shared__ float wsqp[KCODES];              // 2048 B: 1.25 + ||w_k||^2
    __shared__ int idxbuf[256];                 // 1024 B
    __shared__ int hist[KCODES];                // 2048 B block histogram
    __shared__ double sred[8];                  // per-wave sse partials

    const int tid = threadIdx.x;
    const int lane = tid & 63, wv = tid >> 6;   // wv in [0,8)
    const int col = lane & 15, quad = lane >> 4;
    const int ntok0 = blockIdx.x * 256;         // 512 blocks x 256 tokens

    wsqp[tid] = 1.25f;
    hist[tid] = 0;
    __syncthreads();  // B1: wsqp/hist init before use

    // ---- phase 1: pass-0 W staging (codes 0..255) interleaved with all X ----
    // it<4 carries one W chunk (float4-pair); every it carries 4 X dwords.
    const float* gbase = in + (ntok0 >> 12) * CHW + (ntok0 & 4095) + wv * 32 + col;
    short8 ah[2][2];
    float xsq = 0.f;
#pragma unroll
    for (int it = 0; it < 8; ++it) {
        const int sub = it >> 2, c = (it >> 1) & 1, j0 = (it & 1) * 4;
        const float* gp = gbase + sub * 16 + (c * 32 + quad * 8 + j0) * HW;
        const float x0 = gp[0 * HW], x1 = gp[1 * HW], x2 = gp[2 * HW], x3 = gp[3 * HW];

        if (it < 4) {
            const int g = it * 512 + tid;  // [0,2048): 256 codes x 8 chunks
            const int cc = g & 15, qd = (g >> 4) & 3, ch = (g >> 6) & 1, tt = g >> 7;
            const int code = tt * 16 + cc;
            const float4* src = (const float4*)(w + code * 64 + ch * 32 + qd * 8);
            const float4 v0 = src[0], v1 = src[1];
            short8 hv;
            hv[0] = (short)f2bf(v0.x); hv[1] = (short)f2bf(v0.y);
            hv[2] = (short)f2bf(v0.z); hv[3] = (short)f2bf(v0.w);
            hv[4] = (short)f2bf(v1.x); hv[5] = (short)f2bf(v1.y);
            hv[6] = (short)f2bf(v1.z); hv[7] = (short)f2bf(v1.w);
            *(short8*)(wh + g * 8) = hv;
            float ws2 = v0.x * v0.x;
            ws2 = fmaf(v0.y, v0.y, ws2); ws2 = fmaf(v0.z, v0.z, ws2);
            ws2 = fmaf(v0.w, v0.w, ws2); ws2 = fmaf(v1.x, v1.x, ws2);
            ws2 = fmaf(v1.y, v1.y, ws2); ws2 = fmaf(v1.z, v1.z, ws2);
            ws2 = fmaf(v1.w, v1.w, ws2);
            atomicAdd(&wsqp[code], ws2);  // LDS atomic
        }

        ah[sub][c][j0 + 0] = (short)f2bf(-2.0f * x0);
        ah[sub][c][j0 + 1] = (short)f2bf(-2.0f * x1);
        ah[sub][c][j0 + 2] = (short)f2bf(-2.0f * x2);
        ah[sub][c][j0 + 3] = (short)f2bf(-2.0f * x3);
        xsq = fmaf(x0, x0, xsq); xsq = fmaf(x1, x1, xsq);
        xsq = fmaf(x2, x2, xsq); xsq = fmaf(x3, x3, xsq);
    }
    __syncthreads();  // B2: pass-0 wh + wsqp[0:256] complete

    unsigned runkey[2][4];
#pragma unroll
    for (int sub = 0; sub < 2; ++sub)
#pragma unroll
        for (int r = 0; r < 4; ++r) runkey[sub][r] = 0xFFFFFFFFu;

    // ---- scan pass 0: codes 0..255 ----
#pragma unroll 1
    for (int t = 0; t < 16; ++t) {
        const unsigned short* ph = wh + t * 1024 + quad * 128 + col * 8;
        const short8 b0 = *(const short8*)ph;
        const short8 b1 = *(const short8*)(ph + 512);
        const int code = t * 16 + col;
        const float seed = wsqp[code];
#pragma unroll
        for (int sub = 0; sub < 2; ++sub) {
            f32x4 acc = {seed, seed, seed, seed};
            acc = __builtin_amdgcn_mfma_f32_16x16x32_bf16(ah[sub][0], b0, acc, 0, 0, 0);
            acc = __builtin_amdgcn_mfma_f32_16x16x32_bf16(ah[sub][1], b1, acc, 0, 0, 0);
#pragma unroll
            for (int r = 0; r < 4; ++r) {
                const unsigned key = (__float_as_uint(acc[r]) << 9) | code;
                runkey[sub][r] = key < runkey[sub][r] ? key : runkey[sub][r];
            }
        }
    }
    __syncthreads();  // B3: all waves done reading pass-0 wh

    // ---- pass-1 staging (codes 256..511) ----
#pragma unroll
    for (int it = 0; it < 4; ++it) {
        const int g = it * 512 + tid;
        const int cc = g & 15, qd = (g >> 4) & 3, ch = (g >> 6) & 1, tt = g >> 7;
        const int code = 256 + tt * 16 + cc;
        const float4* src = (const float4*)(w + code * 64 + ch * 32 + qd * 8);
        const float4 v0 = src[0], v1 = src[1];
        short8 hv;
        hv[0] = (short)f2bf(v0.x); hv[1] = (short)f2bf(v0.y);
        hv[2] = (short)f2bf(v0.z); hv[3] = (short)f2bf(v0.w);
        hv[4] = (short)f2bf(v1.x); hv[5] = (short)f2bf(v1.y);
        hv[6] = (short)f2bf(v1.z); hv[7] = (short)f2bf(v1.w);
        *(short8*)(wh + g * 8) = hv;
        float ws2 = v0.x * v0.x;
        ws2 = fmaf(v0.y, v0.y, ws2); ws2 = fmaf(v0.z, v0.z, ws2);
        ws2 = fmaf(v0.w, v0.w, ws2); ws2 = fmaf(v1.x, v1.x, ws2);
        ws2 = fmaf(v1.y, v1.y, ws2); ws2 = fmaf(v1.z, v1.z, ws2);
        ws2 = fmaf(v1.w, v1.w, ws2);
        atomicAdd(&wsqp[code], ws2);
    }
    __syncthreads();  // B4: pass-1 wh + wsqp[256:512] complete

    // ---- scan pass 1: codes 256..511 ----
#pragma unroll 1
    for (int t = 0; t < 16; ++t) {
        const unsigned short* ph = wh + t * 1024 + quad * 128 + col * 8;
        const short8 b0 = *(const short8*)ph;
        const short8 b1 = *(const short8*)(ph + 512);
        const int code = 256 + t * 16 + col;
        const float seed = wsqp[code];
#pragma unroll
        for (int sub = 0; sub < 2; ++sub) {
            f32x4 acc = {seed, seed, seed, seed};
            acc = __builtin_amdgcn_mfma_f32_16x16x32_bf16(ah[sub][0], b0, acc, 0, 0, 0);
            acc = __builtin_amdgcn_mfma_f32_16x16x32_bf16(ah[sub][1], b1, acc, 0, 0, 0);
#pragma unroll
            for (int r = 0; r < 4; ++r) {
                const unsigned key = (__float_as_uint(acc[r]) << 9) | code;
                runkey[sub][r] = key < runkey[sub][r] ? key : runkey[sub][r];
            }
        }
    }

    // ---- cross-lane argmin over the 16 code-cols ----
#pragma unroll
    for (int s = 1; s < 16; s <<= 1)
#pragma unroll
        for (int sub = 0; sub < 2; ++sub)
#pragma unroll
            for (int r = 0; r < 4; ++r) {
                const unsigned o = __shfl_xor(runkey[sub][r], s, 64);
                runkey[sub][r] = o < runkey[sub][r] ? o : runkey[sub][r];
            }

    // d_best (exact from key) + publish indices (wave-local consumers only)
    float dsum = 0.f;
    if (col == 0) {
#pragma unroll
        for (int sub = 0; sub < 2; ++sub)
#pragma unroll
            for (int r = 0; r < 4; ++r) {
                const unsigned key = runkey[sub][r];
                idxbuf[wv * 32 + sub * 16 + quad * 4 + r] = (int)(key & 511u);
                dsum += __uint_as_float((key >> 9) | 0x3F800000u) - 1.25f;
            }
    }
    float contrib = xsq + dsum;
#pragma unroll
    for (int off = 32; off > 0; off >>= 1) contrib += __shfl_down(contrib, off, 64);
    if (lane == 0) sred[wv] = (double)contrib;

    // per-wave histogram over wave-local idxbuf (no extra barrier needed)
    if (lane < 32) atomicAdd(&hist[idxbuf[wv * 32 + lane]], 1);

    // ---- epilogue: write w rows only (L2-hot); 4 lanes/token, 2 passes ----
#pragma unroll
    for (int p = 0; p < 2; ++p) {
        const int tl = p * 16 + (lane >> 2), q = lane & 3;
        const int n = ntok0 + wv * 32 + tl;
        const int bidx = idxbuf[wv * 32 + tl];
        const float4* wr = (const float4*)(w + bidx * 64 + q * 16);
        float4* op = (float4*)(out + n * 64 + q * 16);
#pragma unroll
        for (int i = 0; i < 4; ++i) op[i] = wr[i];
    }
    __syncthreads();  // B5: hist + sred complete

    if (!amode) {
        pcounts[(blockIdx.x << 9) + tid] = (unsigned short)hist[tid];
        if (tid == 0) {
            double s = sred[0];
#pragma unroll
            for (int i = 1; i < 8; ++i) s += sred[i];
            ssep[blockIdx.x] = s;
        }
    } else {  // fallback: ws too small for partials
        const int h = hist[tid];
        if (h) atomicAdd(&counts[tid], (float)h);
        if (tid == 0) {
            double s = sred[0];
#pragma unroll
            for (int i = 1; i < 8; ++i) s += sred[i];
            atomicAdd(sse_acc, s);
        }
    }
}

// parallel reduce: thread t owns 4 codes x 1 block-quarter; u16x4 coalesced
__global__ __launch_bounds__(512) void vq_final_p(const unsigned short* __restrict__ pcounts,
                                                  const double* __restrict__ ssep,
                                                  float* __restrict__ out) {
    __shared__ float part[4][512];   // 8 KB: quarter x code
    __shared__ double red[512];
    __shared__ double sred[512];
    const int t = threadIdx.x;
    const int q = t >> 7, c4 = (t & 127) << 2;

    const u16x4* base = (const u16x4*)pcounts + (q << 14) + (c4 >> 2);
    float4 s = {0.f, 0.f, 0.f, 0.f};
#pragma unroll 16
    for (int b = 0; b < 128; ++b) {        // rows q*128 .. q*128+128
        const u16x4 v = base[b << 7];      // stride 512 ushorts = 128 u16x4
        s.x += (float)v[0]; s.y += (float)v[1];
        s.z += (float)v[2]; s.w += (float)v[3];
    }
    *(float4*)&part[q][c4] = s;
    sred[t] = ssep[t];
    __syncthreads();

    const float cnt = part[0][t] + part[1][t] + part[2][t] + part[3][t];
    const double p = (double)cnt / (double)NTOK;
    red[t] = p * log(p + 1e-10);
    __syncthreads();
#pragma unroll
    for (int st = 256; st > 0; st >>= 1) {
        if (t < st) { red[t] += red[t + st]; sred[t] += sred[t + st]; }
        __syncthreads();
    }
    if (t == 0) {
        out[NELEM] = (float)((sred[0] / (double)NELEM) * 1.25);
        out[NELEM + 1] = (float)exp(-red[0]);
    }
}

__global__ __launch_bounds__(512) void vq_final_a(const float* __restrict__ counts,
                                                  const double* __restrict__ sse_acc,
                                                  float* __restrict__ out) {
    __shared__ double red[512];
    const int k = threadIdx.x;
    const double p = (double)counts[k] / (double)NTOK;
    red[k] = p * log(p + 1e-10);
    __syncthreads();
#pragma unroll
    for (int st = 256; st > 0; st >>= 1) {
        if (k < st) red[k] += red[k + st];
        __syncthreads();
    }
    if (k == 0) {
        out[NELEM] = (float)((*sse_acc / (double)NELEM) * 1.25);
        out[NELEM + 1] = (float)exp(-red[0]);
    }
}

extern "C" void kernel_launch(void* const* d_in, const int* in_sizes, int n_in,
                              void* d_out, int out_size, void* d_ws, size_t ws_size,
                              hipStream_t stream) {
    const float* in = (const float*)d_in[0];
    const float* w = (const float*)d_in[1];
    float* out = (float*)d_out;
    char* ws = (char*)d_ws;

    const size_t SS = (size_t)512 * 512 * 2;      // 512 KB of u16 partials
    const size_t need = SS + 512 * 8;             // + ssep f64[512]
    if (ws_size >= need) {
        unsigned short* pcounts = (unsigned short*)ws;
        double* ssep = (double*)(ws + SS);
        vq_main<<<512, 512, 0, stream>>>(in, w, out, pcounts, ssep,
                                         nullptr, nullptr, 0);
        vq_final_p<<<1, 512, 0, stream>>>(pcounts, ssep, out);
    } else {  // fallback: R6-style atomics
        float* counts = (float*)ws;
        double* sse_acc = (double*)(ws + 2048);
        (void)hipMemsetAsync(ws, 0, 2056, stream);
        vq_main<<<512, 512, 0, stream>>>(in, w, out, nullptr, nullptr,
                                         counts, sse_acc, 1);
        vq_final_a<<<1, 512, 0, stream>>>(counts, sse_acc, out);
    }
}